// Round 1
// baseline (200.361 us; speedup 1.0000x reference)
//
#include <hip/hip_runtime.h>
#include <hip/hip_bf16.h>
#include <cstdint>

using bf16   = __bf16;
using bf16x4 = __attribute__((ext_vector_type(4))) __bf16;
using bf16x8 = __attribute__((ext_vector_type(8))) __bf16;
using f32x4  = __attribute__((ext_vector_type(4))) float;

#define MFMA16(a, b, c) __builtin_amdgcn_mfma_f32_16x16x32_bf16((a), (b), (c), 0, 0, 0)

// async global->LDS, 16B per lane; LDS dest = wave-uniform base + lane*16.
__device__ __forceinline__ void load_lds16(const bf16* g, bf16* l) {
    __builtin_amdgcn_global_load_lds(
        (const __attribute__((address_space(1))) void*)g,
        (__attribute__((address_space(3))) void*)l, 16, 0, 0);
}

// ---------------- fused cast fp32 -> bf16 (x, Wq*scale, Wk, Wv) ----------------
__global__ __launch_bounds__(256) void cast_all(const float* __restrict__ x,
                                                const float* __restrict__ Wq,
                                                const float* __restrict__ Wk,
                                                const float* __restrict__ Wv,
                                                bf16* __restrict__ xb,
                                                bf16* __restrict__ wb,
                                                float qscale) {
    int i = blockIdx.x * 256 + threadIdx.x;   // float4 index, 1835008 total
    const float* src; bf16* dst; int off; float scale = 1.0f;
    if (i < 1048576)      { src = x;  dst = xb;              off = i; }
    else if (i < 1310720) { src = Wq; dst = wb;              off = i - 1048576; scale = qscale; }
    else if (i < 1572864) { src = Wk; dst = wb + (1u << 20); off = i - 1310720; }
    else                  { src = Wv; dst = wb + (2u << 20); off = i - 1572864; }
    float4 v = reinterpret_cast<const float4*>(src)[off];
    bf16x4 o;
    o[0] = (bf16)(v.x * scale); o[1] = (bf16)(v.y * scale);
    o[2] = (bf16)(v.z * scale); o[3] = (bf16)(v.w * scale);
    reinterpret_cast<bf16x4*>(dst)[off] = o;
}

// ---------------- fused QKV projection: y = x @ [Wq|Wk|Wv]^T ----------------
// 128x64 tiles (M x N), BK=64 -> 1536 blocks = 6/CU for barrier-drain overlap.
// LDS[row][cc] = global[row][cc ^ (row&7)] (8-elem chunks, conflict-free readback)
__global__ __launch_bounds__(256) void qkv_gemm(const bf16* __restrict__ xb,
                                                const bf16* __restrict__ wb,
                                                bf16* __restrict__ Qo,
                                                bf16* __restrict__ Ko,
                                                bf16* __restrict__ Vt) {
    const int n0 = blockIdx.x * 64;
    const int m0 = blockIdx.y * 128;

    __shared__ __align__(16) bf16 As[128 * 64];   // 16 KB
    __shared__ __align__(16) bf16 Bs[64 * 64];    // 8 KB

    const int t    = threadIdx.x;
    const int lane = t & 63;
    const int wid  = t >> 6;
    const int quad = lane >> 4;
    const int col  = lane & 15;
    const int wm   = wid & 1;      // M half (64)
    const int wn   = wid >> 1;     // N half (32)

    const int rsub = lane >> 3;
    const int csw  = ((lane & 7) ^ rsub) * 8;

    f32x4 acc[4][2] = {};

    const bf16* Ag = &xb[(size_t)(m0 + rsub) * 1024 + csw];
    const bf16* Bg = &wb[(size_t)(n0 + rsub) * 1024 + csw];

    for (int kc = 0; kc < 1024; kc += 64) {
        __syncthreads();
#pragma unroll
        for (int j = 0; j < 4; ++j) {
            const int c = wid * 4 + j;           // 16 A chunk-blocks
            load_lds16(Ag + kc + (size_t)c * 8 * 1024, &As[c * 512]);
        }
#pragma unroll
        for (int j = 0; j < 2; ++j) {
            const int c = wid * 2 + j;           // 8 B chunk-blocks
            load_lds16(Bg + kc + (size_t)c * 8 * 1024, &Bs[c * 512]);
        }
        __syncthreads();

#pragma unroll
        for (int ks = 0; ks < 2; ++ks) {
            const int ca = ((ks * 4 + quad) ^ (col & 7)) * 8;
            bf16x8 a[4], b[2];
#pragma unroll
            for (int i = 0; i < 4; ++i)
                a[i] = *reinterpret_cast<const bf16x8*>(
                    &As[(wm * 64 + i * 16 + col) * 64 + ca]);
#pragma unroll
            for (int i = 0; i < 2; ++i)
                b[i] = *reinterpret_cast<const bf16x8*>(
                    &Bs[(wn * 32 + i * 16 + col) * 64 + ca]);
#pragma unroll
            for (int mt = 0; mt < 4; ++mt)
#pragma unroll
                for (int nt = 0; nt < 2; ++nt)
                    acc[mt][nt] = MFMA16(a[mt], b[nt], acc[mt][nt]);
        }
    }

    const int w = blockIdx.x >> 4;   // 16 n-tiles per 1024 outputs
#pragma unroll
    for (int mt = 0; mt < 4; ++mt) {
#pragma unroll
        for (int nt = 0; nt < 2; ++nt) {
#pragma unroll
            for (int r = 0; r < 4; ++r) {
                int m = m0 + wm * 64 + mt * 16 + quad * 4 + r;
                int n = n0 + wn * 32 + nt * 16 + col;
                int bb = m >> 11, s = m & 2047;
                int n1 = n & 1023;
                int h = n1 >> 6, d = n1 & 63;
                size_t bh = (size_t)(bb * 16 + h);
                bf16 v = (bf16)acc[mt][nt][r];
                if (w == 0)      Qo[(bh * 2048 + s) * 64 + d] = v;
                else if (w == 1) Ko[(bh * 2048 + s) * 64 + d] = v;
                else             Vt[(bh * 64 + d) * 2048 + s] = v;
            }
        }
    }
}

// ---------------- V suffix tile sums (parallel) ----------------
__global__ __launch_bounds__(256) void tail_kernel(const bf16* __restrict__ Vt,
                                                   float* __restrict__ Tail) {
    const int bh = blockIdx.x;
    const bf16* Vg = Vt + (size_t)bh * 64 * 2048;
    float* Tg = Tail + (size_t)bh * 33 * 64;

    __shared__ float ts[64 * 33];
    const int tid = threadIdx.x;

#pragma unroll
    for (int i = 0; i < 8; ++i) {
        int task = i * 256 + tid;          // 0..2047
        int d = task >> 5, tt = task & 31;
        const bf16* p = &Vg[(size_t)d * 2048 + tt * 64];
        float s = 0.0f;
#pragma unroll
        for (int j = 0; j < 8; ++j) {
            bf16x8 v = *reinterpret_cast<const bf16x8*>(p + j * 8);
#pragma unroll
            for (int e = 0; e < 8; ++e) s += (float)v[e];
        }
        ts[d * 33 + tt] = s;
    }
    __syncthreads();

    if (tid < 64) {
        const int d = tid;
        float s = 0.0f;
        Tg[32 * 64 + d] = 0.0f;
        for (int tt = 31; tt >= 1; --tt) {
            s += ts[d * 33 + tt];
            Tg[tt * 64 + d] = s;
        }
    }
}

// ---------------- attention ----------------
// Pairs q-tiles (qt, 31-qt) in one block: np(qt)+np(31-qt) == 17 for all pairs ->
// uniform work, 512 blocks = exactly 2/CU, no makespan tail. The key ranges nest
// (np_a <= 8 < np_b), so both tiles consume the SAME staged K/V chunks for the
// overlap region. K/V LDS is double-buffered with a 2-phase schedule (issue next
// chunk's global_load_lds, compute current, single barrier) so HBM/L2 latency
// hides under QK^T+exp2+PV. Q pre-scaled by log2(e)/32. Multiplicative mask:
// masked score=0 -> p=exp2(0)=1, still counted; fully-masked tail handled by Tail.
__global__ __launch_bounds__(256) void attn_kernel(const bf16* __restrict__ Q,
                                                   const bf16* __restrict__ K,
                                                   const bf16* __restrict__ Vt,
                                                   const float* __restrict__ Tail,
                                                   float* __restrict__ out) {
    const int b   = blockIdx.z;
    const int h   = blockIdx.y;
    const int qta = blockIdx.x;          // 0..15  (light tile)
    const int qtb = 31 - qta;            // 16..31 (heavy tile)
    const int npa = (qta >> 1) + 1;      // 1..8   128-key chunks for tile a
    const int npb = (qtb >> 1) + 1;      // 9..16  128-key chunks for tile b

    const int t    = threadIdx.x;
    const int lane = t & 63;
    const int wid  = t >> 6;
    const int quad = lane >> 4;
    const int col  = lane & 15;

    const int bh = b * 16 + h;
    const bf16* Qg = Q + (size_t)bh * 2048 * 64;
    const bf16* Kg = K + (size_t)bh * 2048 * 64;
    const bf16* Vg = Vt + (size_t)bh * 64 * 2048;

    __shared__ __align__(16) bf16 Ks[2][128 * 64];  // 2 x 16 KB: [key][d], swizzled
    __shared__ __align__(16) bf16 Vs[2][64 * 128];  // 2 x 16 KB: [d][key], swizzled
    __shared__ __align__(16) bf16 Ps[4 * 16 * 72];  // wave-private P
    bf16* Pw = &Ps[wid * 16 * 72];

    const int q0a = qta * 64, q0b = qtb * 64;
    bf16x8 qfa[2], qfb[2];
#pragma unroll
    for (int ks = 0; ks < 2; ++ks) {
        qfa[ks] = *reinterpret_cast<const bf16x8*>(
            &Qg[(size_t)(q0a + wid * 16 + col) * 64 + ks * 32 + quad * 8]);
        qfb[ks] = *reinterpret_cast<const bf16x8*>(
            &Qg[(size_t)(q0b + wid * 16 + col) * 64 + ks * 32 + quad * 8]);
    }

    bf16x8 ones;
#pragma unroll
    for (int i = 0; i < 8; ++i) ones[i] = (bf16)1.0f;

    // init with fully-masked tail beyond 2*np tiles (p == 1 there)
    f32x4 oa[4], ob[4], laa, lab;
    {
        const float tca = 64.0f * (float)(32 - 2 * npa);
        const float tcb = 64.0f * (float)(32 - 2 * npb);
#pragma unroll
        for (int r = 0; r < 4; ++r) { laa[r] = tca; lab[r] = tcb; }
        const float* Tga = Tail + ((size_t)bh * 33 + 2 * npa) * 64;
        const float* Tgb = Tail + ((size_t)bh * 33 + 2 * npb) * 64;
#pragma unroll
        for (int dt = 0; dt < 4; ++dt) {
            float tva = Tga[dt * 16 + col];
            float tvb = Tgb[dt * 16 + col];
#pragma unroll
            for (int r = 0; r < 4; ++r) { oa[dt][r] = tva; ob[dt][r] = tvb; }
        }
    }

    const int qrowa = q0a + wid * 16 + quad * 4;
    const int qrowb = q0b + wid * 16 + quad * 4;

    // K staging: 16 chunk-blocks of 8 rows x 64; V staging: 16 chunk-blocks of 4 rows x 128
    const int rsubK = lane >> 3;
    const int cswK  = ((lane & 7) ^ rsubK) * 8;
    const int rV    = lane >> 4;
    const int ccV   = lane & 15;

    auto stage = [&](int cc, int buf) {
        const int s0 = cc * 128;
#pragma unroll
        for (int jj = 0; jj < 4; ++jj) {
            const int c = wid * 4 + jj;
            load_lds16(&Kg[(size_t)(s0 + c * 8 + rsubK) * 64 + cswK], &Ks[buf][c * 512]);
            const int d = c * 4 + rV;
            load_lds16(&Vg[(size_t)d * 2048 + s0 + ((ccV ^ (d & 15)) * 8)], &Vs[buf][c * 512]);
        }
    };

    auto compute = [&](const bf16x8* qf, f32x4* o, f32x4& la, int qrow,
                       bool diag, int s0, int buf) {
        // S' = (Q*log2e/32) K^T over 8 key-subtiles
        f32x4 sv[8] = {};
#pragma unroll
        for (int ks = 0; ks < 2; ++ks) {
            const int ca = ((ks * 4 + quad) ^ (col & 7)) * 8;
#pragma unroll
            for (int nt = 0; nt < 8; ++nt) {
                bf16x8 kb = *reinterpret_cast<const bf16x8*>(
                    &Ks[buf][(nt * 16 + col) * 64 + ca]);
                sv[nt] = MFMA16(qf[ks], kb, sv[nt]);
            }
        }

        // multiplicative mask only on the diagonal chunk of this tile
        if (diag) {
#pragma unroll
            for (int nt = 0; nt < 8; ++nt) {
                int kidx = s0 + nt * 16 + col;
#pragma unroll
                for (int r = 0; r < 4; ++r)
                    if (kidx > qrow + r) sv[nt][r] = 0.0f;
            }
        }

        // PV in two 64-key halves, reusing wave-private Ps
#pragma unroll
        for (int hh = 0; hh < 2; ++hh) {
#pragma unroll
            for (int nt = 0; nt < 4; ++nt)
#pragma unroll
                for (int r = 0; r < 4; ++r)
                    Pw[(quad * 4 + r) * 72 + nt * 16 + col] =
                        (bf16)__builtin_amdgcn_exp2f(sv[hh * 4 + nt][r]);

#pragma unroll
            for (int gg = 0; gg < 2; ++gg) {
                bf16x8 pa = *reinterpret_cast<const bf16x8*>(
                    &Pw[col * 72 + gg * 32 + quad * 8]);
                la = MFMA16(pa, ones, la);
                const int g = hh * 2 + gg;
#pragma unroll
                for (int dt = 0; dt < 4; ++dt) {
                    bf16x8 vb = *reinterpret_cast<const bf16x8*>(
                        &Vs[buf][(dt * 16 + col) * 128 + ((g * 4 + quad) ^ col) * 8]);
                    o[dt] = MFMA16(pa, vb, o[dt]);
                }
            }
        }
    };

    stage(0, 0);
    __syncthreads();

    for (int cc = 0; cc < npb; ++cc) {
        const int cur = cc & 1;
        if (cc + 1 < npb) stage(cc + 1, cur ^ 1);   // loads in flight across compute
        const int s0 = cc * 128;
        compute(qfb, ob, lab, qrowb, cc == npb - 1, s0, cur);
        if (cc < npa)
            compute(qfa, oa, laa, qrowa, cc == npa - 1, s0, cur);
        __syncthreads();   // waits own vmcnt(0) then barrier: next buffer ready,
                           // and all waves done reading buf[cur] before overwrite
    }

#pragma unroll
    for (int r = 0; r < 4; ++r) {
        float inva = __builtin_amdgcn_rcpf(laa[r]);
        float invb = __builtin_amdgcn_rcpf(lab[r]);
#pragma unroll
        for (int dt = 0; dt < 4; ++dt) {
            int d = dt * 16 + col;
            out[((size_t)b * 2048 + qrowa + r) * 1024 + h * 64 + d] = oa[dt][r] * inva;
            out[((size_t)b * 2048 + qrowb + r) * 1024 + h * 64 + d] = ob[dt][r] * invb;
        }
    }
}

extern "C" void kernel_launch(void* const* d_in, const int* in_sizes, int n_in,
                              void* d_out, int out_size, void* d_ws, size_t ws_size,
                              hipStream_t stream) {
    const float* x  = (const float*)d_in[0];
    const float* Wq = (const float*)d_in[1];
    const float* Wk = (const float*)d_in[2];
    const float* Wv = (const float*)d_in[3];
    float* out = (float*)d_out;

    char* ws = (char*)d_ws;
    bf16*  xb   = (bf16*)(ws);                        // 8 MB
    bf16*  wb   = (bf16*)(ws + (size_t)(8  << 20));   // 6 MB [Wq|Wk|Wv]
    bf16*  Qb   = (bf16*)(ws + (size_t)(14 << 20));   // 8 MB [B,H,S,D] (pre-scaled)
    bf16*  Kb   = (bf16*)(ws + (size_t)(22 << 20));   // 8 MB [B,H,S,D]
    bf16*  Vtb  = (bf16*)(ws + (size_t)(30 << 20));   // 8 MB [B,H,D,S]
    float* Tail = (float*)(ws + (size_t)(38 << 20));  // 264 KB

    const float QSCALE = 1.44269504088896f / 32.0f;   // log2(e)/sqrt(E)

    cast_all<<<7168, 256, 0, stream>>>(x, Wq, Wk, Wv, xb, wb, QSCALE);

    qkv_gemm<<<dim3(48, 32), 256, 0, stream>>>(xb, wb, Qb, Kb, Vtb);

    tail_kernel<<<32, 256, 0, stream>>>(Vtb, Tail);

    attn_kernel<<<dim3(16, 16, 2), 256, 0, stream>>>(Qb, Kb, Vtb, Tail, out);
}

// Round 2
// 195.869 us; speedup vs baseline: 1.0229x; 1.0229x over previous
//
#include <hip/hip_runtime.h>
#include <hip/hip_bf16.h>
#include <cstdint>

using bf16   = __bf16;
using bf16x4 = __attribute__((ext_vector_type(4))) __bf16;
using bf16x8 = __attribute__((ext_vector_type(8))) __bf16;
using f32x4  = __attribute__((ext_vector_type(4))) float;

#define MFMA16(a, b, c) __builtin_amdgcn_mfma_f32_16x16x32_bf16((a), (b), (c), 0, 0, 0)

// async global->LDS, 16B per lane; LDS dest = wave-uniform base + lane*16.
__device__ __forceinline__ void load_lds16(const bf16* g, bf16* l) {
    __builtin_amdgcn_global_load_lds(
        (const __attribute__((address_space(1))) void*)g,
        (__attribute__((address_space(3))) void*)l, 16, 0, 0);
}

// ---------------- fused cast fp32 -> bf16 (x, Wq*scale, Wk, Wv) ----------------
__global__ __launch_bounds__(256) void cast_all(const float* __restrict__ x,
                                                const float* __restrict__ Wq,
                                                const float* __restrict__ Wk,
                                                const float* __restrict__ Wv,
                                                bf16* __restrict__ xb,
                                                bf16* __restrict__ wb,
                                                float qscale) {
    int i = blockIdx.x * 256 + threadIdx.x;   // float4 index, 1835008 total
    const float* src; bf16* dst; int off; float scale = 1.0f;
    if (i < 1048576)      { src = x;  dst = xb;              off = i; }
    else if (i < 1310720) { src = Wq; dst = wb;              off = i - 1048576; scale = qscale; }
    else if (i < 1572864) { src = Wk; dst = wb + (1u << 20); off = i - 1310720; }
    else                  { src = Wv; dst = wb + (2u << 20); off = i - 1572864; }
    float4 v = reinterpret_cast<const float4*>(src)[off];
    bf16x4 o;
    o[0] = (bf16)(v.x * scale); o[1] = (bf16)(v.y * scale);
    o[2] = (bf16)(v.z * scale); o[3] = (bf16)(v.w * scale);
    reinterpret_cast<bf16x4*>(dst)[off] = o;
}

// ---------------- fused QKV projection: y = x @ [Wq|Wk|Wv]^T ----------------
// 128x64 tiles (M x N), BK=64 -> 1536 blocks = 6/CU for barrier-drain overlap.
// LDS[row][cc] = global[row][cc ^ (row&7)] (8-elem chunks, conflict-free readback)
__global__ __launch_bounds__(256) void qkv_gemm(const bf16* __restrict__ xb,
                                                const bf16* __restrict__ wb,
                                                bf16* __restrict__ Qo,
                                                bf16* __restrict__ Ko,
                                                bf16* __restrict__ Vt) {
    const int n0 = blockIdx.x * 64;
    const int m0 = blockIdx.y * 128;

    __shared__ __align__(16) bf16 As[128 * 64];   // 16 KB
    __shared__ __align__(16) bf16 Bs[64 * 64];    // 8 KB

    const int t    = threadIdx.x;
    const int lane = t & 63;
    const int wid  = t >> 6;
    const int quad = lane >> 4;
    const int col  = lane & 15;
    const int wm   = wid & 1;      // M half (64)
    const int wn   = wid >> 1;     // N half (32)

    const int rsub = lane >> 3;
    const int csw  = ((lane & 7) ^ rsub) * 8;

    f32x4 acc[4][2] = {};

    const bf16* Ag = &xb[(size_t)(m0 + rsub) * 1024 + csw];
    const bf16* Bg = &wb[(size_t)(n0 + rsub) * 1024 + csw];

    for (int kc = 0; kc < 1024; kc += 64) {
        __syncthreads();
#pragma unroll
        for (int j = 0; j < 4; ++j) {
            const int c = wid * 4 + j;           // 16 A chunk-blocks
            load_lds16(Ag + kc + (size_t)c * 8 * 1024, &As[c * 512]);
        }
#pragma unroll
        for (int j = 0; j < 2; ++j) {
            const int c = wid * 2 + j;           // 8 B chunk-blocks
            load_lds16(Bg + kc + (size_t)c * 8 * 1024, &Bs[c * 512]);
        }
        __syncthreads();

#pragma unroll
        for (int ks = 0; ks < 2; ++ks) {
            const int ca = ((ks * 4 + quad) ^ (col & 7)) * 8;
            bf16x8 a[4], b[2];
#pragma unroll
            for (int i = 0; i < 4; ++i)
                a[i] = *reinterpret_cast<const bf16x8*>(
                    &As[(wm * 64 + i * 16 + col) * 64 + ca]);
#pragma unroll
            for (int i = 0; i < 2; ++i)
                b[i] = *reinterpret_cast<const bf16x8*>(
                    &Bs[(wn * 32 + i * 16 + col) * 64 + ca]);
#pragma unroll
            for (int mt = 0; mt < 4; ++mt)
#pragma unroll
                for (int nt = 0; nt < 2; ++nt)
                    acc[mt][nt] = MFMA16(a[mt], b[nt], acc[mt][nt]);
        }
    }

    const int w = blockIdx.x >> 4;   // 16 n-tiles per 1024 outputs
#pragma unroll
    for (int mt = 0; mt < 4; ++mt) {
#pragma unroll
        for (int nt = 0; nt < 2; ++nt) {
#pragma unroll
            for (int r = 0; r < 4; ++r) {
                int m = m0 + wm * 64 + mt * 16 + quad * 4 + r;
                int n = n0 + wn * 32 + nt * 16 + col;
                int bb = m >> 11, s = m & 2047;
                int n1 = n & 1023;
                int h = n1 >> 6, d = n1 & 63;
                size_t bh = (size_t)(bb * 16 + h);
                bf16 v = (bf16)acc[mt][nt][r];
                if (w == 0)      Qo[(bh * 2048 + s) * 64 + d] = v;
                else if (w == 1) Ko[(bh * 2048 + s) * 64 + d] = v;
                else             Vt[(bh * 64 + d) * 2048 + s] = v;
            }
        }
    }
}

// ---------------- V suffix tile sums (parallel) ----------------
__global__ __launch_bounds__(256) void tail_kernel(const bf16* __restrict__ Vt,
                                                   float* __restrict__ Tail) {
    const int bh = blockIdx.x;
    const bf16* Vg = Vt + (size_t)bh * 64 * 2048;
    float* Tg = Tail + (size_t)bh * 33 * 64;

    __shared__ float ts[64 * 33];
    const int tid = threadIdx.x;

#pragma unroll
    for (int i = 0; i < 8; ++i) {
        int task = i * 256 + tid;          // 0..2047
        int d = task >> 5, tt = task & 31;
        const bf16* p = &Vg[(size_t)d * 2048 + tt * 64];
        float s = 0.0f;
#pragma unroll
        for (int j = 0; j < 8; ++j) {
            bf16x8 v = *reinterpret_cast<const bf16x8*>(p + j * 8);
#pragma unroll
            for (int e = 0; e < 8; ++e) s += (float)v[e];
        }
        ts[d * 33 + tt] = s;
    }
    __syncthreads();

    if (tid < 64) {
        const int d = tid;
        float s = 0.0f;
        Tg[32 * 64 + d] = 0.0f;
        for (int tt = 31; tt >= 1; --tt) {
            s += ts[d * 33 + tt];
            Tg[tt * 64 + d] = s;
        }
    }
}

// ---------------- attention ----------------
// 64-key chunks, double-buffered K/V via REGISTER staging (T14): global_load ->
// VGPRs (no LDS-alias vmcnt drain, loads fly under compute) -> ds_write into the
// buffer not being read. LDS stays 41 KB -> 3 blocks/CU. Swapped QK^T
// (mfma(K,Q)) puts 4 consecutive keys of one q-row in each lane, so the P
// scatter is 4x ds_write_b64 instead of 16x ds_write_b16; P layout on the read
// side (PV A-operand) is unchanged. Q pre-scaled by log2(e)/32. Multiplicative
// mask: masked score=0 -> p=exp2(0)=1, still counted; tail handled by Tail sums.
__global__ __launch_bounds__(256) void attn_kernel(const bf16* __restrict__ Q,
                                                   const bf16* __restrict__ K,
                                                   const bf16* __restrict__ Vt,
                                                   const float* __restrict__ Tail,
                                                   float* __restrict__ out) {
    const int b = blockIdx.z;
    const int h = blockIdx.y;
    const int j  = ((blockIdx.y >> 3) ^ blockIdx.z) & 1;
    const int qt = j ? (31 - (int)blockIdx.x) : (int)blockIdx.x;
    const int q0 = qt * 64;
    const int nt = qt + 1;               // 64-key tiles to process

    const int t    = threadIdx.x;
    const int lane = t & 63;
    const int wid  = t >> 6;
    const int quad = lane >> 4;
    const int col  = lane & 15;

    const int bh = b * 16 + h;
    const bf16* Qg = Q + (size_t)bh * 2048 * 64;
    const bf16* Kg = K + (size_t)bh * 2048 * 64;
    const bf16* Vg = Vt + (size_t)bh * 64 * 2048;

    __shared__ __align__(16) bf16 Ks[2][64 * 64];   // 2 x 8 KB: [key][d], swizzled
    __shared__ __align__(16) bf16 Vs[2][64 * 64];   // 2 x 8 KB: [d][key], swizzled
    __shared__ __align__(16) bf16 Ps[4 * 16 * 72];  // wave-private P [16 q][64+8 key]
    bf16* Pw = &Ps[wid * 16 * 72];

    bf16x8 qf[2];
#pragma unroll
    for (int ks = 0; ks < 2; ++ks)
        qf[ks] = *reinterpret_cast<const bf16x8*>(
            &Qg[(size_t)(q0 + wid * 16 + col) * 64 + ks * 32 + quad * 8]);

    bf16x8 ones;
#pragma unroll
    for (int i = 0; i < 8; ++i) ones[i] = (bf16)1.0f;

    // init with fully-masked tail beyond nt tiles (p == 1 there)
    f32x4 o[4];
    f32x4 la;
    {
        const float tc = 64.0f * (float)(32 - nt);
#pragma unroll
        for (int r = 0; r < 4; ++r) la[r] = tc;
        const float* Tg = Tail + ((size_t)bh * 33 + nt) * 64;
#pragma unroll
        for (int dt = 0; dt < 4; ++dt) {
            float tv = Tg[dt * 16 + col];
#pragma unroll
            for (int r = 0; r < 4; ++r) o[dt][r] = tv;
        }
    }

    const int qrow_o = q0 + wid * 16 + quad * 4;  // output rows of this lane
    const int qcol   = q0 + wid * 16 + col;       // q-index of this lane's sv cols

    // staging decomposition: per wave 2 chunk-blocks of 8 rows x 64 elems each;
    // global src pre-swizzled (chunk c8^r8), LDS dest linear -> LDS[r][c]=G[r][c^(r&7)]
    const int r8  = lane >> 3;          // 0..7
    const int c8s = ((lane & 7) ^ r8) * 8;

    float4 kr[2], vr[2];

    for (int cc0 = 0; cc0 < 1; ++cc0) { // scope
        const int s0 = 0;
#pragma unroll
        for (int jj = 0; jj < 2; ++jj) {
            const int c = wid * 2 + jj;
            kr[jj] = *reinterpret_cast<const float4*>(
                &Kg[(size_t)(s0 + c * 8 + r8) * 64 + c8s]);
            vr[jj] = *reinterpret_cast<const float4*>(
                &Vg[(size_t)(c * 8 + r8) * 2048 + s0 + c8s]);
        }
#pragma unroll
        for (int jj = 0; jj < 2; ++jj) {
            const int c = wid * 2 + jj;
            *reinterpret_cast<float4*>(&Ks[0][c * 512 + lane * 8]) = kr[jj];
            *reinterpret_cast<float4*>(&Vs[0][c * 512 + lane * 8]) = vr[jj];
        }
    }
    __syncthreads();

    for (int cc = 0; cc < nt; ++cc) {
        const int cur  = cc & 1;
        const bool last = (cc == nt - 1);

        // issue next chunk's loads to registers (in flight across compute)
        if (!last) {
            const int s0 = (cc + 1) * 64;
#pragma unroll
            for (int jj = 0; jj < 2; ++jj) {
                const int c = wid * 2 + jj;
                kr[jj] = *reinterpret_cast<const float4*>(
                    &Kg[(size_t)(s0 + c * 8 + r8) * 64 + c8s]);
                vr[jj] = *reinterpret_cast<const float4*>(
                    &Vg[(size_t)(c * 8 + r8) * 2048 + s0 + c8s]);
            }
        }

        // ---- compute chunk cc from buf cur ----
        // S'^T = K (Q*log2e/32)^T : sv[ntk][r] = S[key = cc*64+ntk*16+quad*4+r][q = qcol]
        f32x4 sv[4] = {};
        __builtin_amdgcn_s_setprio(1);
#pragma unroll
        for (int ks = 0; ks < 2; ++ks) {
            const int ca = ((ks * 4 + quad) ^ (col & 7)) * 8;
#pragma unroll
            for (int ntk = 0; ntk < 4; ++ntk) {
                bf16x8 kb = *reinterpret_cast<const bf16x8*>(
                    &Ks[cur][(ntk * 16 + col) * 64 + ca]);
                sv[ntk] = MFMA16(kb, qf[ks], sv[ntk]);   // swapped operands
            }
        }
        __builtin_amdgcn_s_setprio(0);

        // multiplicative mask on the diagonal chunk only
        if (last) {
            const int s0 = cc * 64;
#pragma unroll
            for (int ntk = 0; ntk < 4; ++ntk) {
#pragma unroll
                for (int r = 0; r < 4; ++r) {
                    int kidx = s0 + ntk * 16 + quad * 4 + r;
                    if (kidx > qcol) sv[ntk][r] = 0.0f;
                }
            }
        }

        // exp2 + pack 4 consecutive keys -> one ds_write_b64 per ntk
#pragma unroll
        for (int ntk = 0; ntk < 4; ++ntk) {
            bf16x4 pw;
#pragma unroll
            for (int r = 0; r < 4; ++r)
                pw[r] = (bf16)__builtin_amdgcn_exp2f(sv[ntk][r]);
            *reinterpret_cast<bf16x4*>(&Pw[col * 72 + ntk * 16 + quad * 4]) = pw;
        }

        // PV over two 32-key groups
#pragma unroll
        for (int gg = 0; gg < 2; ++gg) {
            bf16x8 pa = *reinterpret_cast<const bf16x8*>(
                &Pw[col * 72 + gg * 32 + quad * 8]);
            __builtin_amdgcn_s_setprio(1);
            la = MFMA16(pa, ones, la);
#pragma unroll
            for (int dt = 0; dt < 4; ++dt) {
                bf16x8 vb = *reinterpret_cast<const bf16x8*>(
                    &Vs[cur][(dt * 16 + col) * 64 + (((gg * 4 + quad) ^ (col & 7))) * 8]);
                o[dt] = MFMA16(pa, vb, o[dt]);
            }
            __builtin_amdgcn_s_setprio(0);
        }

        // write prefetched regs into the other buffer (it was last read in
        // iter cc-1, separated by that iter's barrier). vmcnt wait lands here.
        if (!last) {
#pragma unroll
            for (int jj = 0; jj < 2; ++jj) {
                const int c = wid * 2 + jj;
                *reinterpret_cast<float4*>(&Ks[cur ^ 1][c * 512 + lane * 8]) = kr[jj];
                *reinterpret_cast<float4*>(&Vs[cur ^ 1][c * 512 + lane * 8]) = vr[jj];
            }
        }
        __syncthreads();
    }

#pragma unroll
    for (int r = 0; r < 4; ++r) {
        float inv = __builtin_amdgcn_rcpf(la[r]);
#pragma unroll
        for (int dt = 0; dt < 4; ++dt) {
            int d = dt * 16 + col;
            out[((size_t)b * 2048 + qrow_o + r) * 1024 + h * 64 + d] = o[dt][r] * inv;
        }
    }
}

extern "C" void kernel_launch(void* const* d_in, const int* in_sizes, int n_in,
                              void* d_out, int out_size, void* d_ws, size_t ws_size,
                              hipStream_t stream) {
    const float* x  = (const float*)d_in[0];
    const float* Wq = (const float*)d_in[1];
    const float* Wk = (const float*)d_in[2];
    const float* Wv = (const float*)d_in[3];
    float* out = (float*)d_out;

    char* ws = (char*)d_ws;
    bf16*  xb   = (bf16*)(ws);                        // 8 MB
    bf16*  wb   = (bf16*)(ws + (size_t)(8  << 20));   // 6 MB [Wq|Wk|Wv]
    bf16*  Qb   = (bf16*)(ws + (size_t)(14 << 20));   // 8 MB [B,H,S,D] (pre-scaled)
    bf16*  Kb   = (bf16*)(ws + (size_t)(22 << 20));   // 8 MB [B,H,S,D]
    bf16*  Vtb  = (bf16*)(ws + (size_t)(30 << 20));   // 8 MB [B,H,D,S]
    float* Tail = (float*)(ws + (size_t)(38 << 20));  // 264 KB

    const float QSCALE = 1.44269504088896f / 32.0f;   // log2(e)/sqrt(E)

    cast_all<<<7168, 256, 0, stream>>>(x, Wq, Wk, Wv, xb, wb, QSCALE);

    qkv_gemm<<<dim3(48, 32), 256, 0, stream>>>(xb, wb, Qb, Kb, Vtb);

    tail_kernel<<<32, 256, 0, stream>>>(Vtb, Tail);

    attn_kernel<<<dim3(32, 16, 2), 256, 0, stream>>>(Qb, Kb, Vtb, Tail, out);
}